// Round 13
// baseline (64.268 us; speedup 1.0000x reference)
//
#include <hip/hip_runtime.h>
#include <stdint.h>
#include <math.h>

#define NN 4096
#define DIN 1024
#define DOUT 512
#define ALPHA 0.2f

typedef __attribute__((ext_vector_type(8))) short short8;
typedef __attribute__((ext_vector_type(4))) float f32x4;

__device__ __forceinline__ unsigned short f2bf(float f) {
    uint32_t u = __float_as_uint(f);
    u += 0x7fffu + ((u >> 16) & 1u);
    return (unsigned short)(u >> 16);
}

__device__ __forceinline__ void async16(const void* g, void* l) {
    __builtin_amdgcn_global_load_lds(
        (const __attribute__((address_space(1))) uint32_t*)g,
        (__attribute__((address_space(3))) uint32_t*)l, 16, 0, 0);
}

// ---------------- K1: mask + prep fused (all input-independent work).
// blocks 0..2047:    adj stream -> u16 masks (2 rows/block, 8 forced loads)
// blocks 2048..2303: wt = bf16(W^T) pre-swizzled (block 2048 zeroes colacc)
// blocks 2304..2559: wa1 = Wf@a1, wa2 = Wf@a2 (wave per row)
__global__ __launch_bounds__(256) void k_maskprep(const float* __restrict__ adj,
    const float* __restrict__ W, const float* __restrict__ Wf,
    const float* __restrict__ a1, const float* __restrict__ a2,
    unsigned short* __restrict__ wt, float* __restrict__ wa1,
    float* __restrict__ wa2, unsigned short* __restrict__ bits16,
    float* __restrict__ colacc) {
    int tid = threadIdx.x;
    if (blockIdx.x < 2048) {
        int row0 = blockIdx.x * 2;
        const float4* a0 = (const float4*)(adj + (size_t)row0 * NN);
        const float4* a1v = (const float4*)(adj + (size_t)(row0 + 1) * NN);
        float4 v0 = a0[tid];        float4 v1 = a0[tid + 256];
        float4 v2 = a0[tid + 512];  float4 v3 = a0[tid + 768];
        float4 v4 = a1v[tid];       float4 v5 = a1v[tid + 256];
        float4 v6 = a1v[tid + 512]; float4 v7 = a1v[tid + 768];
        __builtin_amdgcn_sched_barrier(0);   // all 8 loads issue first (rule #18)
        unsigned int m0 = 0, m1 = 0;
#define MB(M, V, J)                                            \
        M |= (((V).x != 0.f) ? 1u : 0u) << (4 * (J));          \
        M |= (((V).y != 0.f) ? 1u : 0u) << (4 * (J) + 1);      \
        M |= (((V).z != 0.f) ? 1u : 0u) << (4 * (J) + 2);      \
        M |= (((V).w != 0.f) ? 1u : 0u) << (4 * (J) + 3);
        MB(m0, v0, 0) MB(m0, v1, 1) MB(m0, v2, 2) MB(m0, v3, 3)
        MB(m1, v4, 0) MB(m1, v5, 1) MB(m1, v6, 2) MB(m1, v7, 3)
#undef MB
        bits16[(size_t)row0 * 256 + tid]       = (unsigned short)m0;
        bits16[(size_t)row0 * 256 + 256 + tid] = (unsigned short)m1;
    } else if (blockIdx.x < 2304) {
        if (blockIdx.x == 2048) {
#pragma unroll
            for (int i = 0; i < 16; ++i) colacc[tid + 256 * i] = 0.f;
        }
        int idx = blockIdx.x - 2048;
        int bx = idx & 7, gy = idx >> 3;
        int n = bx * 64 + (tid & 63);
        int g = gy * 4 + (tid >> 6);          // k-granule 0..127
        float v[8];
#pragma unroll
        for (int j = 0; j < 8; ++j) v[j] = W[(size_t)(g * 8 + j) * DOUT + n];
        union { unsigned short u[8]; uint4 q; } pk;
#pragma unroll
        for (int j = 0; j < 8; ++j) pk.u[j] = f2bf(v[j]);
        int sw = (n >> 1) & 3;
        int p  = (g & ~3) | ((g & 3) ^ sw);
        *(uint4*)(wt + (size_t)n * DIN + p * 8) = pk.q;
    } else {
        int row  = (blockIdx.x - 2304) * 4 + (tid >> 6);
        int lane = tid & 63;
        const float* wr = Wf + (size_t)row * DOUT;
        float s1 = 0.f, s2 = 0.f;
        for (int k = lane; k < DOUT; k += 64) {
            float w = wr[k];
            s1 += w * a1[k];
            s2 += w * a2[k];
        }
        for (int off = 32; off; off >>= 1) {
            s1 += __shfl_down(s1, off);
            s2 += __shfl_down(s2, off);
        }
        if (lane == 0) { wa1[row] = s1; wa2[row] = s2; }
    }
}

// ---------------- K2: f1,f2 GEMV + x -> bf16 (pre-swizzled), wave per row
__global__ __launch_bounds__(256) void k_fx(const float* __restrict__ x,
    const float* __restrict__ wa1, const float* __restrict__ wa2,
    const float* __restrict__ b1, const float* __restrict__ b2,
    float* __restrict__ f1, float* __restrict__ f2,
    unsigned short* __restrict__ xb) {
    int row  = blockIdx.x * 4 + (threadIdx.x >> 6);
    int lane = threadIdx.x & 63;
    const float* xr = x + (size_t)row * DIN + lane * 16;
    float xv[16];
    *(float4*)&xv[0]  = *(const float4*)(xr);
    *(float4*)&xv[4]  = *(const float4*)(xr + 4);
    *(float4*)&xv[8]  = *(const float4*)(xr + 8);
    *(float4*)&xv[12] = *(const float4*)(xr + 12);
    __builtin_amdgcn_sched_barrier(0);   // all 4 loads in flight
    const float* w1 = wa1 + lane * 16;
    const float* w2 = wa2 + lane * 16;
    float s1 = 0.f, s2 = 0.f;
#pragma unroll
    for (int j = 0; j < 16; ++j) {
        s1 += xv[j] * w1[j];
        s2 += xv[j] * w2[j];
    }
    union { unsigned short u[8]; uint4 q; } pk0, pk1;
#pragma unroll
    for (int j = 0; j < 8; ++j) { pk0.u[j] = f2bf(xv[j]); pk1.u[j] = f2bf(xv[8 + j]); }
    int sw = (row >> 1) & 3;
    int g0 = lane * 2, g1 = lane * 2 + 1;
    int p0 = (g0 & ~3) | ((g0 & 3) ^ sw);
    int p1 = (g1 & ~3) | ((g1 & 3) ^ sw);
    unsigned short* xrow = xb + (size_t)row * DIN;
    *(uint4*)(xrow + p0 * 8) = pk0.q;
    *(uint4*)(xrow + p1 * 8) = pk1.q;
    for (int off = 32; off; off >>= 1) {
        s1 += __shfl_down(s1, off);
        s2 += __shfl_down(s2, off);
    }
    if (lane == 0) { f1[row] = s1 + b1[0]; f2[row] = s2 + b2[0]; }
}

// ---------------- K3: Z + colsum scatter (wave per row, 4 rows/block).
// Walk 1: Z_row (butterfly reduce -> rZ known to ALL lanes).
// Walk 2: scatter coefs[row][j] = e_ij * rZ_row into colacc via atomicAdd.
// Bit b of u64 word at lane l -> col j = 16*l + 4*(b>>4) + 1024*((b>>2)&3) + (b&3)
__global__ __launch_bounds__(256) void k_zs(const unsigned long long* __restrict__ bits,
                                            const float* __restrict__ f1,
                                            const float* __restrict__ f2,
                                            float* __restrict__ rZ_out,
                                            float* __restrict__ colacc) {
    int row  = blockIdx.x * 4 + (threadIdx.x >> 6);
    int lane = threadIdx.x & 63;
    unsigned long long w = bits[(size_t)row * 64 + lane];
    float f1r = f1[row];
    float z = 0.f;
    unsigned long long w1 = w;
    while (w1) {
        int b = __builtin_ctzll(w1);
        w1 &= w1 - 1;
        int j = 16 * lane + 4 * (b >> 4) + 1024 * ((b >> 2) & 3) + (b & 3);
        float l = f1r + f2[j];
        z += __expf((l >= 0.f) ? l : ALPHA * l);
    }
#pragma unroll
    for (int off = 32; off; off >>= 1) z += __shfl_xor(z, off);
    float rZ = 1.0f / z;
    if (lane == 0) rZ_out[row] = rZ;
    while (w) {
        int b = __builtin_ctzll(w);
        w &= w - 1;
        int j = 16 * lane + 4 * (b >> 4) + 1024 * ((b >> 2) & 3) + (b & 3);
        float l = f1r + f2[j];
        float e = (l >= 0.f) ? l : ALPHA * l;
        atomicAdd(&colacc[j], __expf(e) * rZ);
    }
}

// ---------------- K4: out = relu(diag(s) @ (xb @ Wt^T)), bf16 MFMA.
// Round-11 4-wave kernel + cheap s prologue (128 coalesced loads, hidden
// under STAGE(0)'s vmcnt wait).
__global__ __launch_bounds__(256) void k_gemm(const unsigned short* __restrict__ xb,
                                              const unsigned short* __restrict__ wt,
                                              const float* __restrict__ f1,
                                              const float* __restrict__ f2,
                                              const float* __restrict__ rZ,
                                              const float* __restrict__ colacc,
                                              float* __restrict__ out) {
    __shared__ __align__(16) unsigned short As[2][128][32];
    __shared__ __align__(16) unsigned short Bs[2][64][32];
    __shared__ float s_lds[128];
    int lid = blockIdx.y * gridDim.x + blockIdx.x;   // 0..255
    int xcd = lid & 7, idx = lid >> 3;
    int by = xcd * 4 + (idx & 3);                    // 0..31
    int bx = idx >> 2;                               // 0..7
    int bm = by * 128, bn = bx * 64;

    int tid = threadIdx.x, wid = tid >> 6, lane = tid & 63;
    int wr = wid >> 1, wc = wid & 1;

    int srow = lane >> 2, sg = lane & 3;
    const unsigned short* ga0 = xb + (size_t)(bm + wid * 32 + srow) * DIN + sg * 8;
    const unsigned short* gb0 = wt + (size_t)(bn + wid * 16 + srow) * DIN + sg * 8;

    int r15 = lane & 15, gl = lane >> 4;
    int gofs = (gl ^ ((r15 >> 1) & 3)) * 8;          // XOR-swizzled read offset

    f32x4 acc[4][2] = {};

#define STAGE(BUF, K0) do {                                              \
        async16(ga0 + (K0),            &As[BUF][wid * 32][0]);           \
        async16(ga0 + (K0) + 16 * DIN, &As[BUF][wid * 32 + 16][0]);      \
        async16(gb0 + (K0),            &Bs[BUF][wid * 16][0]);           \
    } while (0)

#define COMPUTE(BUF) do {                                                \
        const unsigned short* pa = &As[BUF][wr * 64 + r15][gofs];        \
        const unsigned short* pb = &Bs[BUF][wc * 32 + r15][gofs];        \
        short8 af0 = *(const short8*)(pa);                               \
        short8 af1 = *(const short8*)(pa + 16 * 32);                     \
        short8 af2 = *(const short8*)(pa + 32 * 32);                     \
        short8 af3 = *(const short8*)(pa + 48 * 32);                     \
        short8 bf0 = *(const short8*)(pb);                               \
        short8 bf1 = *(const short8*)(pb + 16 * 32);                     \
        acc[0][0] = __builtin_amdgcn_mfma_f32_16x16x32_bf16(af0, bf0, acc[0][0], 0, 0, 0); \
        acc[0][1] = __builtin_amdgcn_mfma_f32_16x16x32_bf16(af0, bf1, acc[0][1], 0, 0, 0); \
        acc[1][0] = __builtin_amdgcn_mfma_f32_16x16x32_bf16(af1, bf0, acc[1][0], 0, 0, 0); \
        acc[1][1] = __builtin_amdgcn_mfma_f32_16x16x32_bf16(af1, bf1, acc[1][1], 0, 0, 0); \
        acc[2][0] = __builtin_amdgcn_mfma_f32_16x16x32_bf16(af2, bf0, acc[2][0], 0, 0, 0); \
        acc[2][1] = __builtin_amdgcn_mfma_f32_16x16x32_bf16(af2, bf1, acc[2][1], 0, 0, 0); \
        acc[3][0] = __builtin_amdgcn_mfma_f32_16x16x32_bf16(af3, bf0, acc[3][0], 0, 0, 0); \
        acc[3][1] = __builtin_amdgcn_mfma_f32_16x16x32_bf16(af3, bf1, acc[3][1], 0, 0, 0); \
    } while (0)

    STAGE(0, 0);
    if (tid < 128) {
        int r = bm + tid;
        float l   = f1[r] + f2[r];
        float cjj = __expf((l >= 0.f) ? l : ALPHA * l) * rZ[r];
        s_lds[tid] = (cjj + 1.0f) / (1.5f + 0.5f * colacc[r]);
    }
    asm volatile("s_waitcnt vmcnt(0)" ::: "memory");
    __syncthreads();
    int cur = 0;
    for (int t = 0; t < (DIN / 32) - 1; ++t) {
        STAGE(cur ^ 1, (t + 1) * 32);
        COMPUTE(cur);
        asm volatile("s_waitcnt vmcnt(0)" ::: "memory");
        __syncthreads();
        cur ^= 1;
    }
    COMPUTE(cur);

#pragma unroll
    for (int mi = 0; mi < 4; ++mi) {
        int lrow0 = wr * 64 + mi * 16 + gl * 4;
#pragma unroll
        for (int ni = 0; ni < 2; ++ni) {
            int ccol = bn + wc * 32 + ni * 16 + r15;
#pragma unroll
            for (int r = 0; r < 4; ++r) {
                int lrow = lrow0 + r;
                float v = acc[mi][ni][r] * s_lds[lrow];
                out[(size_t)(bm + lrow) * DOUT + ccol] = fmaxf(v, 0.f);
            }
        }
    }
#undef STAGE
#undef COMPUTE
}

extern "C" void kernel_launch(void* const* d_in, const int* in_sizes, int n_in,
                              void* d_out, int out_size, void* d_ws, size_t ws_size,
                              hipStream_t stream) {
    const float* x   = (const float*)d_in[0];
    const float* adj = (const float*)d_in[1];
    const float* Wf  = (const float*)d_in[2];
    const float* a1  = (const float*)d_in[3];
    const float* b1  = (const float*)d_in[4];
    const float* a2  = (const float*)d_in[5];
    const float* b2  = (const float*)d_in[6];
    const float* W   = (const float*)d_in[7];
    float* out = (float*)d_out;

    char* w = (char*)d_ws;
    float* wa1 = (float*)(w + 0);
    float* wa2 = (float*)(w + 4096);
    float* f1  = (float*)(w + 16384);
    float* f2  = (float*)(w + 32768);
    float* rZ  = (float*)(w + 49152);
    float* colacc = (float*)(w + 65536);
    unsigned short* bits16 = (unsigned short*)(w + 98304);           // 2 MB
    unsigned short* xb = (unsigned short*)(w + 2195456);             // 8 MB
    unsigned short* wt = (unsigned short*)(w + 10584064);            // 1 MB

    k_maskprep<<<2560, 256, 0, stream>>>(adj, W, Wf, a1, a2, wt, wa1, wa2,
                                         bits16, colacc);
    k_fx<<<1024, 256, 0, stream>>>(x, wa1, wa2, b1, b2, f1, f2, xb);
    k_zs<<<1024, 256, 0, stream>>>((const unsigned long long*)bits16, f1, f2,
                                   rZ, colacc);
    dim3 gg(8, 32);
    k_gemm<<<gg, 256, 0, stream>>>(xb, wt, f1, f2, rZ, colacc, out);
}

// Round 15
// 52.853 us; speedup vs baseline: 1.2160x; 1.2160x over previous
//
#include <hip/hip_runtime.h>
#include <stdint.h>
#include <math.h>

#define NN 4096
#define DIN 1024
#define DOUT 512
#define ALPHA 0.2f

typedef __attribute__((ext_vector_type(8))) short short8;
typedef __attribute__((ext_vector_type(4))) float f32x4;

__device__ __forceinline__ unsigned short f2bf(float f) {
    uint32_t u = __float_as_uint(f);
    u += 0x7fffu + ((u >> 16) & 1u);
    return (unsigned short)(u >> 16);
}

__device__ __forceinline__ f32x4 ntload(const float* p) {
    return __builtin_nontemporal_load((const f32x4*)p);
}

__device__ __forceinline__ void async16(const void* g, void* l) {
    __builtin_amdgcn_global_load_lds(
        (const __attribute__((address_space(1))) uint32_t*)g,
        (__attribute__((address_space(3))) uint32_t*)l, 16, 0, 0);
}

// ---------------- K1: fused prep (identical to round 11).
__global__ __launch_bounds__(256) void k_prep(const float* __restrict__ W,
                                              const float* __restrict__ Wf,
                                              const float* __restrict__ a1,
                                              const float* __restrict__ a2,
                                              unsigned short* __restrict__ wt,
                                              float* __restrict__ wa1,
                                              float* __restrict__ wa2) {
    int tid = threadIdx.x;
    if (blockIdx.x < 256) {
        int bx = blockIdx.x & 7, gy = blockIdx.x >> 3;
        int n = bx * 64 + (tid & 63);
        int g = gy * 4 + (tid >> 6);          // k-granule 0..127
        float v[8];
#pragma unroll
        for (int j = 0; j < 8; ++j) v[j] = W[(size_t)(g * 8 + j) * DOUT + n];
        union { unsigned short u[8]; uint4 q; } pk;
#pragma unroll
        for (int j = 0; j < 8; ++j) pk.u[j] = f2bf(v[j]);
        int sw = (n >> 1) & 3;
        int p  = (g & ~3) | ((g & 3) ^ sw);
        *(uint4*)(wt + (size_t)n * DIN + p * 8) = pk.q;
    } else {
        int row  = (blockIdx.x - 256) * 4 + (tid >> 6);
        int lane = tid & 63;
        const float* wr = Wf + (size_t)row * DOUT;
        float s1 = 0.f, s2 = 0.f;
        for (int k = lane; k < DOUT; k += 64) {
            float w = wr[k];
            s1 += w * a1[k];
            s2 += w * a2[k];
        }
        for (int off = 32; off; off >>= 1) {
            s1 += __shfl_down(s1, off);
            s2 += __shfl_down(s2, off);
        }
        if (lane == 0) { wa1[row] = s1; wa2[row] = s2; }
    }
}

// ---------------- K2: fused mask-builder + fx.
// blocks 0..1023: adj stream -> u16 masks. 4 rows/block, 16 NONTEMPORAL
//   f32x4 loads per thread all in flight (sched_barrier fence) -> deep MLP,
//   no L2 allocation churn.
// blocks 1024..2047: f1,f2 GEMV + x -> bf16 (wave per row), nt x loads.
__global__ __launch_bounds__(256) void k_maskfx(const float* __restrict__ adj,
    const float* __restrict__ x,
    const float* __restrict__ wa1, const float* __restrict__ wa2,
    const float* __restrict__ b1, const float* __restrict__ b2,
    float* __restrict__ f1, float* __restrict__ f2,
    unsigned short* __restrict__ xb,
    unsigned short* __restrict__ bits16) {
    int tid = threadIdx.x;
    if (blockIdx.x < 1024) {
        int row0 = blockIdx.x * 4;
        const float* a0 = adj + (size_t)row0 * NN;
        f32x4 v[16];
#pragma unroll
        for (int r = 0; r < 4; ++r) {
#pragma unroll
            for (int i = 0; i < 4; ++i)
                v[r * 4 + i] = ntload(a0 + (size_t)r * NN + (tid + 256 * i) * 4);
        }
        __builtin_amdgcn_sched_barrier(0);   // all 16 loads issue before any use
        unsigned int m[4] = {0, 0, 0, 0};
#pragma unroll
        for (int r = 0; r < 4; ++r) {
#pragma unroll
            for (int i = 0; i < 4; ++i) {
                f32x4 q = v[r * 4 + i];
                m[r] |= ((q.x != 0.f) ? 1u : 0u) << (4 * i);
                m[r] |= ((q.y != 0.f) ? 1u : 0u) << (4 * i + 1);
                m[r] |= ((q.z != 0.f) ? 1u : 0u) << (4 * i + 2);
                m[r] |= ((q.w != 0.f) ? 1u : 0u) << (4 * i + 3);
            }
        }
#pragma unroll
        for (int r = 0; r < 4; ++r)
            bits16[(size_t)(row0 + r) * 256 + tid] = (unsigned short)m[r];
    } else {
        int row  = (blockIdx.x - 1024) * 4 + (tid >> 6);
        int lane = tid & 63;
        const float* xr = x + (size_t)row * DIN + lane * 16;
        f32x4 q0 = ntload(xr);
        f32x4 q1 = ntload(xr + 4);
        f32x4 q2 = ntload(xr + 8);
        f32x4 q3 = ntload(xr + 12);
        __builtin_amdgcn_sched_barrier(0);   // all 4 loads in flight
        float xv[16];
        *(f32x4*)&xv[0]  = q0;
        *(f32x4*)&xv[4]  = q1;
        *(f32x4*)&xv[8]  = q2;
        *(f32x4*)&xv[12] = q3;
        const float* w1 = wa1 + lane * 16;
        const float* w2 = wa2 + lane * 16;
        float s1 = 0.f, s2 = 0.f;
#pragma unroll
        for (int j = 0; j < 16; ++j) {
            s1 += xv[j] * w1[j];
            s2 += xv[j] * w2[j];
        }
        union { unsigned short u[8]; uint4 q; } pk0, pk1;
#pragma unroll
        for (int j = 0; j < 8; ++j) { pk0.u[j] = f2bf(xv[j]); pk1.u[j] = f2bf(xv[8 + j]); }
        int sw = (row >> 1) & 3;
        int g0 = lane * 2, g1 = lane * 2 + 1;
        int p0 = (g0 & ~3) | ((g0 & 3) ^ sw);
        int p1 = (g1 & ~3) | ((g1 & 3) ^ sw);
        unsigned short* xrow = xb + (size_t)row * DIN;
        *(uint4*)(xrow + p0 * 8) = pk0.q;
        *(uint4*)(xrow + p1 * 8) = pk1.q;
        for (int off = 32; off; off >>= 1) {
            s1 += __shfl_down(s1, off);
            s2 += __shfl_down(s2, off);
        }
        if (lane == 0) { f1[row] = s1 + b1[0]; f2[row] = s2 + b2[0]; }
    }
}

// ---------------- K3: Z via bitmask walk (wave per row, 4 rows/block) -> rZ
__global__ __launch_bounds__(256) void k_z(const unsigned long long* __restrict__ bits,
                                           const float* __restrict__ f1,
                                           const float* __restrict__ f2,
                                           float* __restrict__ rZ_out) {
    int row  = blockIdx.x * 4 + (threadIdx.x >> 6);
    int lane = threadIdx.x & 63;
    unsigned long long w = bits[(size_t)row * 64 + lane];
    float f1r = f1[row];
    float z = 0.f;
    while (w) {
        int b = __builtin_ctzll(w);
        w &= w - 1;
        int j = 16 * lane + 4 * (b >> 4) + 1024 * ((b >> 2) & 3) + (b & 3);
        float l = f1r + f2[j];
        z += __expf((l >= 0.f) ? l : ALPHA * l);
    }
    for (int off = 32; off; off >>= 1) z += __shfl_down(z, off);
    if (lane == 0) rZ_out[row] = 1.0f / z;
}

// ---------------- K4: colsum via bitmask walk (wave per row) -> s
__global__ __launch_bounds__(256) void k_s(const unsigned long long* __restrict__ bits,
                                           const float* __restrict__ f1,
                                           const float* __restrict__ f2,
                                           const float* __restrict__ rZ,
                                           float* __restrict__ s_out) {
    int row  = blockIdx.x * 4 + (threadIdx.x >> 6);
    int lane = threadIdx.x & 63;
    unsigned long long w = bits[(size_t)row * 64 + lane];
    float f2r = f2[row];
    float sum = 0.f;
    while (w) {
        int b = __builtin_ctzll(w);
        w &= w - 1;
        int j = 16 * lane + 4 * (b >> 4) + 1024 * ((b >> 2) & 3) + (b & 3);
        float l = f1[j] + f2r;
        float e = (l >= 0.f) ? l : ALPHA * l;
        sum += __expf(e) * rZ[j];
    }
    for (int off = 32; off; off >>= 1) sum += __shfl_down(sum, off);
    if (lane == 0) {
        float l   = f1[row] + f2r;
        float e   = (l >= 0.f) ? l : ALPHA * l;
        float cjj = __expf(e) * rZ[row];
        s_out[row] = (cjj + 1.0f) / (1.5f + 0.5f * sum);
    }
}

// ---------------- K5: out = relu(diag(s) @ (xb @ Wt^T)), bf16 MFMA (round 11)
__global__ __launch_bounds__(256) void k_gemm(const unsigned short* __restrict__ xb,
                                              const unsigned short* __restrict__ wt,
                                              const float* __restrict__ s,
                                              float* __restrict__ out) {
    __shared__ __align__(16) unsigned short As[2][128][32];
    __shared__ __align__(16) unsigned short Bs[2][64][32];
    int lid = blockIdx.y * gridDim.x + blockIdx.x;   // 0..255
    int xcd = lid & 7, idx = lid >> 3;
    int by = xcd * 4 + (idx & 3);                    // 0..31
    int bx = idx >> 2;                               // 0..7
    int bm = by * 128, bn = bx * 64;

    int tid = threadIdx.x, wid = tid >> 6, lane = tid & 63;
    int wr = wid >> 1, wc = wid & 1;

    int srow = lane >> 2, sg = lane & 3;
    const unsigned short* ga0 = xb + (size_t)(bm + wid * 32 + srow) * DIN + sg * 8;
    const unsigned short* gb0 = wt + (size_t)(bn + wid * 16 + srow) * DIN + sg * 8;

    int r15 = lane & 15, gl = lane >> 4;
    int gofs = (gl ^ ((r15 >> 1) & 3)) * 8;          // XOR-swizzled read offset

    f32x4 acc[4][2] = {};

#define STAGE(BUF, K0) do {                                              \
        async16(ga0 + (K0),            &As[BUF][wid * 32][0]);           \
        async16(ga0 + (K0) + 16 * DIN, &As[BUF][wid * 32 + 16][0]);      \
        async16(gb0 + (K0),            &Bs[BUF][wid * 16][0]);           \
    } while (0)

#define COMPUTE(BUF) do {                                                \
        const unsigned short* pa = &As[BUF][wr * 64 + r15][gofs];        \
        const unsigned short* pb = &Bs[BUF][wc * 32 + r15][gofs];        \
        short8 af0 = *(const short8*)(pa);                               \
        short8 af1 = *(const short8*)(pa + 16 * 32);                     \
        short8 af2 = *(const short8*)(pa + 32 * 32);                     \
        short8 af3 = *(const short8*)(pa + 48 * 32);                     \
        short8 bf0 = *(const short8*)(pb);                               \
        short8 bf1 = *(const short8*)(pb + 16 * 32);                     \
        acc[0][0] = __builtin_amdgcn_mfma_f32_16x16x32_bf16(af0, bf0, acc[0][0], 0, 0, 0); \
        acc[0][1] = __builtin_amdgcn_mfma_f32_16x16x32_bf16(af0, bf1, acc[0][1], 0, 0, 0); \
        acc[1][0] = __builtin_amdgcn_mfma_f32_16x16x32_bf16(af1, bf0, acc[1][0], 0, 0, 0); \
        acc[1][1] = __builtin_amdgcn_mfma_f32_16x16x32_bf16(af1, bf1, acc[1][1], 0, 0, 0); \
        acc[2][0] = __builtin_amdgcn_mfma_f32_16x16x32_bf16(af2, bf0, acc[2][0], 0, 0, 0); \
        acc[2][1] = __builtin_amdgcn_mfma_f32_16x16x32_bf16(af2, bf1, acc[2][1], 0, 0, 0); \
        acc[3][0] = __builtin_amdgcn_mfma_f32_16x16x32_bf16(af3, bf0, acc[3][0], 0, 0, 0); \
        acc[3][1] = __builtin_amdgcn_mfma_f32_16x16x32_bf16(af3, bf1, acc[3][1], 0, 0, 0); \
    } while (0)

    STAGE(0, 0);
    asm volatile("s_waitcnt vmcnt(0)" ::: "memory");
    __syncthreads();
    int cur = 0;
    for (int t = 0; t < (DIN / 32) - 1; ++t) {
        STAGE(cur ^ 1, (t + 1) * 32);
        COMPUTE(cur);
        asm volatile("s_waitcnt vmcnt(0)" ::: "memory");
        __syncthreads();
        cur ^= 1;
    }
    COMPUTE(cur);

#pragma unroll
    for (int mi = 0; mi < 4; ++mi) {
        int crow0 = bm + wr * 64 + mi * 16 + gl * 4;
#pragma unroll
        for (int ni = 0; ni < 2; ++ni) {
            int ccol = bn + wc * 32 + ni * 16 + r15;
#pragma unroll
            for (int r = 0; r < 4; ++r) {
                int row = crow0 + r;
                float v = acc[mi][ni][r] * s[row];
                out[(size_t)row * DOUT + ccol] = fmaxf(v, 0.f);
            }
        }
    }
#undef STAGE
#undef COMPUTE
}

extern "C" void kernel_launch(void* const* d_in, const int* in_sizes, int n_in,
                              void* d_out, int out_size, void* d_ws, size_t ws_size,
                              hipStream_t stream) {
    const float* x   = (const float*)d_in[0];
    const float* adj = (const float*)d_in[1];
    const float* Wf  = (const float*)d_in[2];
    const float* a1  = (const float*)d_in[3];
    const float* b1  = (const float*)d_in[4];
    const float* a2  = (const float*)d_in[5];
    const float* b2  = (const float*)d_in[6];
    const float* W   = (const float*)d_in[7];
    float* out = (float*)d_out;

    char* w = (char*)d_ws;
    float* wa1 = (float*)(w + 0);
    float* wa2 = (float*)(w + 4096);
    float* f1  = (float*)(w + 16384);
    float* f2  = (float*)(w + 32768);
    float* rZ  = (float*)(w + 49152);
    float* s   = (float*)(w + 65536);
    unsigned short* bits16 = (unsigned short*)(w + 98304);           // 2 MB
    unsigned short* xb = (unsigned short*)(w + 2195456);             // 8 MB
    unsigned short* wt = (unsigned short*)(w + 10584064);            // 1 MB

    k_prep<<<512, 256, 0, stream>>>(W, Wf, a1, a2, wt, wa1, wa2);
    k_maskfx<<<2048, 256, 0, stream>>>(adj, x, wa1, wa2, b1, b2, f1, f2, xb, bits16);
    k_z<<<1024, 256, 0, stream>>>((const unsigned long long*)bits16, f1, f2, rZ);
    k_s<<<1024, 256, 0, stream>>>((const unsigned long long*)bits16, f1, f2, rZ, s);
    dim3 gg(8, 32);
    k_gemm<<<gg, 256, 0, stream>>>(xb, wt, s, out);
}

// Round 16
// 49.379 us; speedup vs baseline: 1.3015x; 1.0704x over previous
//
#include <hip/hip_runtime.h>
#include <stdint.h>
#include <math.h>

#define NN 4096
#define DIN 1024
#define DOUT 512
#define ALPHA 0.2f

typedef __attribute__((ext_vector_type(8))) short short8;
typedef __attribute__((ext_vector_type(4))) float f32x4;

__device__ __forceinline__ unsigned short f2bf(float f) {
    uint32_t u = __float_as_uint(f);
    u += 0x7fffu + ((u >> 16) & 1u);
    return (unsigned short)(u >> 16);
}

__device__ __forceinline__ void async16(const void* g, void* l) {
    __builtin_amdgcn_global_load_lds(
        (const __attribute__((address_space(1))) uint32_t*)g,
        (__attribute__((address_space(3))) uint32_t*)l, 16, 0, 0);
}

// ---------------- K1: fused prep (identical to round 11).
__global__ __launch_bounds__(256) void k_prep(const float* __restrict__ W,
                                              const float* __restrict__ Wf,
                                              const float* __restrict__ a1,
                                              const float* __restrict__ a2,
                                              unsigned short* __restrict__ wt,
                                              float* __restrict__ wa1,
                                              float* __restrict__ wa2) {
    int tid = threadIdx.x;
    if (blockIdx.x < 256) {
        int bx = blockIdx.x & 7, gy = blockIdx.x >> 3;
        int n = bx * 64 + (tid & 63);
        int g = gy * 4 + (tid >> 6);          // k-granule 0..127
        float v[8];
#pragma unroll
        for (int j = 0; j < 8; ++j) v[j] = W[(size_t)(g * 8 + j) * DOUT + n];
        union { unsigned short u[8]; uint4 q; } pk;
#pragma unroll
        for (int j = 0; j < 8; ++j) pk.u[j] = f2bf(v[j]);
        int sw = (n >> 1) & 3;
        int p  = (g & ~3) | ((g & 3) ^ sw);
        *(uint4*)(wt + (size_t)n * DIN + p * 8) = pk.q;
    } else {
        int row  = (blockIdx.x - 256) * 4 + (tid >> 6);
        int lane = tid & 63;
        const float* wr = Wf + (size_t)row * DOUT;
        float s1 = 0.f, s2 = 0.f;
        for (int k = lane; k < DOUT; k += 64) {
            float w = wr[k];
            s1 += w * a1[k];
            s2 += w * a2[k];
        }
        for (int off = 32; off; off >>= 1) {
            s1 += __shfl_down(s1, off);
            s2 += __shfl_down(s2, off);
        }
        if (lane == 0) { wa1[row] = s1; wa2[row] = s2; }
    }
}

// ---------------- K2: fused mask-builder + fx (identical to round 11).
__global__ __launch_bounds__(256) void k_maskfx(const float* __restrict__ adj,
    const float* __restrict__ x,
    const float* __restrict__ wa1, const float* __restrict__ wa2,
    const float* __restrict__ b1, const float* __restrict__ b2,
    float* __restrict__ f1, float* __restrict__ f2,
    unsigned short* __restrict__ xb,
    unsigned short* __restrict__ bits16) {
    int tid = threadIdx.x;
    if (blockIdx.x < 2048) {
        int row0 = blockIdx.x * 2;
        const float4* a0 = (const float4*)(adj + (size_t)row0 * NN);
        const float4* a1v = (const float4*)(adj + (size_t)(row0 + 1) * NN);
        float4 v0 = a0[tid];        float4 v1 = a0[tid + 256];
        float4 v2 = a0[tid + 512];  float4 v3 = a0[tid + 768];
        float4 v4 = a1v[tid];       float4 v5 = a1v[tid + 256];
        float4 v6 = a1v[tid + 512]; float4 v7 = a1v[tid + 768];
        __builtin_amdgcn_sched_barrier(0);   // all 8 loads issue first (rule #18)
        unsigned int m0 = 0, m1 = 0;
#define MB(M, V, J)                                            \
        M |= (((V).x != 0.f) ? 1u : 0u) << (4 * (J));          \
        M |= (((V).y != 0.f) ? 1u : 0u) << (4 * (J) + 1);      \
        M |= (((V).z != 0.f) ? 1u : 0u) << (4 * (J) + 2);      \
        M |= (((V).w != 0.f) ? 1u : 0u) << (4 * (J) + 3);
        MB(m0, v0, 0) MB(m0, v1, 1) MB(m0, v2, 2) MB(m0, v3, 3)
        MB(m1, v4, 0) MB(m1, v5, 1) MB(m1, v6, 2) MB(m1, v7, 3)
#undef MB
        bits16[(size_t)row0 * 256 + tid]       = (unsigned short)m0;
        bits16[(size_t)row0 * 256 + 256 + tid] = (unsigned short)m1;
    } else {
        int row  = (blockIdx.x - 2048) * 4 + (tid >> 6);
        int lane = tid & 63;
        const float* xr = x + (size_t)row * DIN + lane * 16;
        float xv[16];
        *(float4*)&xv[0]  = *(const float4*)(xr);
        *(float4*)&xv[4]  = *(const float4*)(xr + 4);
        *(float4*)&xv[8]  = *(const float4*)(xr + 8);
        *(float4*)&xv[12] = *(const float4*)(xr + 12);
        __builtin_amdgcn_sched_barrier(0);   // all 4 loads in flight
        const float* w1 = wa1 + lane * 16;
        const float* w2 = wa2 + lane * 16;
        float s1 = 0.f, s2 = 0.f;
#pragma unroll
        for (int j = 0; j < 16; ++j) {
            s1 += xv[j] * w1[j];
            s2 += xv[j] * w2[j];
        }
        union { unsigned short u[8]; uint4 q; } pk0, pk1;
#pragma unroll
        for (int j = 0; j < 8; ++j) { pk0.u[j] = f2bf(xv[j]); pk1.u[j] = f2bf(xv[8 + j]); }
        int sw = (row >> 1) & 3;
        int g0 = lane * 2, g1 = lane * 2 + 1;
        int p0 = (g0 & ~3) | ((g0 & 3) ^ sw);
        int p1 = (g1 & ~3) | ((g1 & 3) ^ sw);
        unsigned short* xrow = xb + (size_t)row * DIN;
        *(uint4*)(xrow + p0 * 8) = pk0.q;
        *(uint4*)(xrow + p1 * 8) = pk1.q;
        for (int off = 32; off; off >>= 1) {
            s1 += __shfl_down(s1, off);
            s2 += __shfl_down(s2, off);
        }
        if (lane == 0) { f1[row] = s1 + b1[0]; f2[row] = s2 + b2[0]; }
    }
}

// ---------------- K3: Z via bitmask walk (wave per row, 4 rows/block) -> rZ
__global__ __launch_bounds__(256) void k_z(const unsigned long long* __restrict__ bits,
                                           const float* __restrict__ f1,
                                           const float* __restrict__ f2,
                                           float* __restrict__ rZ_out) {
    int row  = blockIdx.x * 4 + (threadIdx.x >> 6);
    int lane = threadIdx.x & 63;
    unsigned long long w = bits[(size_t)row * 64 + lane];
    float f1r = f1[row];
    float z = 0.f;
    while (w) {
        int b = __builtin_ctzll(w);
        w &= w - 1;
        int j = 16 * lane + 4 * (b >> 4) + 1024 * ((b >> 2) & 3) + (b & 3);
        float l = f1r + f2[j];
        z += __expf((l >= 0.f) ? l : ALPHA * l);
    }
    for (int off = 32; off; off >>= 1) z += __shfl_down(z, off);
    if (lane == 0) rZ_out[row] = 1.0f / z;
}

// ---------------- K4: colsum via bitmask walk (wave per row) -> s
__global__ __launch_bounds__(256) void k_s(const unsigned long long* __restrict__ bits,
                                           const float* __restrict__ f1,
                                           const float* __restrict__ f2,
                                           const float* __restrict__ rZ,
                                           float* __restrict__ s_out) {
    int row  = blockIdx.x * 4 + (threadIdx.x >> 6);
    int lane = threadIdx.x & 63;
    unsigned long long w = bits[(size_t)row * 64 + lane];
    float f2r = f2[row];
    float sum = 0.f;
    while (w) {
        int b = __builtin_ctzll(w);
        w &= w - 1;
        int j = 16 * lane + 4 * (b >> 4) + 1024 * ((b >> 2) & 3) + (b & 3);
        float l = f1[j] + f2r;
        float e = (l >= 0.f) ? l : ALPHA * l;
        sum += __expf(e) * rZ[j];
    }
    for (int off = 32; off; off >>= 1) sum += __shfl_down(sum, off);
    if (lane == 0) {
        float l   = f1[row] + f2r;
        float e   = (l >= 0.f) ? l : ALPHA * l;
        float cjj = __expf(e) * rZ[row];
        s_out[row] = (cjj + 1.0f) / (1.5f + 0.5f * sum);
    }
}

// ---------------- K5: out = relu(diag(s) @ (xb @ Wt^T)), bf16 MFMA.
// CHANGED: 64x64 tile, 512 blocks -> 2 blocks/CU so vmcnt/barrier drains of
// one block hide under the other block's MFMAs (m114 wave-overlap).
__global__ __launch_bounds__(256) void k_gemm(const unsigned short* __restrict__ xb,
                                              const unsigned short* __restrict__ wt,
                                              const float* __restrict__ s,
                                              float* __restrict__ out) {
    __shared__ __align__(16) unsigned short As[2][64][32];
    __shared__ __align__(16) unsigned short Bs[2][64][32];
    // XCD-chunked remap: 512 blocks, 64/XCD -> 8 consecutive M-strips x 8 N.
    int lid = blockIdx.y * gridDim.x + blockIdx.x;   // 0..511
    int xcd = lid & 7, idx = lid >> 3;               // idx 0..63
    int by = xcd * 8 + (idx & 7);                    // 0..63
    int bx = idx >> 3;                               // 0..7
    int bm = by * 64, bn = bx * 64;

    int tid = threadIdx.x, wid = tid >> 6, lane = tid & 63;
    int wr = wid >> 1, wc = wid & 1;                 // 2x2 wave grid of 32x32

    int srow = lane >> 2, sg = lane & 3;
    const unsigned short* ga0 = xb + (size_t)(bm + wid * 16 + srow) * DIN + sg * 8;
    const unsigned short* gb0 = wt + (size_t)(bn + wid * 16 + srow) * DIN + sg * 8;

    int r15 = lane & 15, gl = lane >> 4;
    int gofs = (gl ^ ((r15 >> 1) & 3)) * 8;          // XOR-swizzled read offset

    f32x4 acc[2][2] = {};

#define STAGE(BUF, K0) do {                                              \
        async16(ga0 + (K0), &As[BUF][wid * 16][0]);                      \
        async16(gb0 + (K0), &Bs[BUF][wid * 16][0]);                      \
    } while (0)

#define COMPUTE(BUF) do {                                                \
        const unsigned short* pa = &As[BUF][wr * 32 + r15][gofs];        \
        const unsigned short* pb = &Bs[BUF][wc * 32 + r15][gofs];        \
        short8 af0 = *(const short8*)(pa);                               \
        short8 af1 = *(const short8*)(pa + 16 * 32);                     \
        short8 bf0 = *(const short8*)(pb);                               \
        short8 bf1 = *(const short8*)(pb + 16 * 32);                     \
        acc[0][0] = __builtin_amdgcn_mfma_f32_16x16x32_bf16(af0, bf0, acc[0][0], 0, 0, 0); \
        acc[0][1] = __builtin_amdgcn_mfma_f32_16x16x32_bf16(af0, bf1, acc[0][1], 0, 0, 0); \
        acc[1][0] = __builtin_amdgcn_mfma_f32_16x16x32_bf16(af1, bf0, acc[1][0], 0, 0, 0); \
        acc[1][1] = __builtin_amdgcn_mfma_f32_16x16x32_bf16(af1, bf1, acc[1][1], 0, 0, 0); \
    } while (0)

    STAGE(0, 0);
    asm volatile("s_waitcnt vmcnt(0)" ::: "memory");
    __syncthreads();
    int cur = 0;
    for (int t = 0; t < (DIN / 32) - 1; ++t) {
        STAGE(cur ^ 1, (t + 1) * 32);
        COMPUTE(cur);
        asm volatile("s_waitcnt vmcnt(0)" ::: "memory");
        __syncthreads();
        cur ^= 1;
    }
    COMPUTE(cur);

#pragma unroll
    for (int mi = 0; mi < 2; ++mi) {
        int crow0 = bm + wr * 32 + mi * 16 + gl * 4;
#pragma unroll
        for (int ni = 0; ni < 2; ++ni) {
            int ccol = bn + wc * 32 + ni * 16 + r15;
#pragma unroll
            for (int r = 0; r < 4; ++r) {
                int row = crow0 + r;
                float v = acc[mi][ni][r] * s[row];
                out[(size_t)row * DOUT + ccol] = fmaxf(v, 0.f);
            }
        }
    }
#undef STAGE
#undef COMPUTE
}

extern "C" void kernel_launch(void* const* d_in, const int* in_sizes, int n_in,
                              void* d_out, int out_size, void* d_ws, size_t ws_size,
                              hipStream_t stream) {
    const float* x   = (const float*)d_in[0];
    const float* adj = (const float*)d_in[1];
    const float* Wf  = (const float*)d_in[2];
    const float* a1  = (const float*)d_in[3];
    const float* b1  = (const float*)d_in[4];
    const float* a2  = (const float*)d_in[5];
    const float* b2  = (const float*)d_in[6];
    const float* W   = (const float*)d_in[7];
    float* out = (float*)d_out;

    char* w = (char*)d_ws;
    float* wa1 = (float*)(w + 0);
    float* wa2 = (float*)(w + 4096);
    float* f1  = (float*)(w + 16384);
    float* f2  = (float*)(w + 32768);
    float* rZ  = (float*)(w + 49152);
    float* s   = (float*)(w + 65536);
    unsigned short* bits16 = (unsigned short*)(w + 98304);           // 2 MB
    unsigned short* xb = (unsigned short*)(w + 2195456);             // 8 MB
    unsigned short* wt = (unsigned short*)(w + 10584064);            // 1 MB

    k_prep<<<512, 256, 0, stream>>>(W, Wf, a1, a2, wt, wa1, wa2);
    k_maskfx<<<3072, 256, 0, stream>>>(adj, x, wa1, wa2, b1, b2, f1, f2, xb, bits16);
    k_z<<<1024, 256, 0, stream>>>((const unsigned long long*)bits16, f1, f2, rZ);
    k_s<<<1024, 256, 0, stream>>>((const unsigned long long*)bits16, f1, f2, rZ, s);
    dim3 gg(8, 64);
    k_gemm<<<gg, 256, 0, stream>>>(xb, wt, s, out);
}